// Round 6
// baseline (2209.432 us; speedup 1.0000x reference)
//
#include <hip/hip_runtime.h>

typedef unsigned short ushort_t;
typedef unsigned long long u64;
typedef __attribute__((ext_vector_type(8))) __bf16 bf16x8;
typedef __attribute__((ext_vector_type(4))) float f32x4;

#define B 256
#define TENC 512
#define TDEC 64
#define DIN 64
#define HD 512
#define OD 512
#define GG 256          // 16 batch-groups x 16 unit-groups
#define NGRP 16         // WGs per batch-group (unit-groups)
#define KTOT 576        // 512 (h) + 64 (x)
#define KI 18           // K iters of 32
#define NT 512          // threads per block
#define SLOTQ (16 * 256 * 16)   // u64s per h slot: [ug 16][row 256][pair 16]

__device__ __forceinline__ float b2f(ushort_t v) {
  union { unsigned u; float f; } x; x.u = ((unsigned)v) << 16; return x.f;
}
__device__ __forceinline__ ushort_t f2b(float f) {
  union { float f; unsigned u; } x; x.f = f;
  unsigned r = x.u + 0x7fffu + ((x.u >> 16) & 1u);   // RNE
  return (ushort_t)(r >> 16);
}
__device__ __forceinline__ float sigmf(float x) { return 1.f / (1.f + __expf(-x)); }
__device__ __forceinline__ float tanhf_fast(float x) {
  float e = __expf(2.f * x);
  return 1.f - 2.f / (e + 1.f);
}
__device__ __forceinline__ float ld_elem(const void* p, size_t i, bool f32) {
  return f32 ? ((const float*)p)[i] : b2f(((const ushort_t*)p)[i]);
}
__device__ __forceinline__ bf16x8 cvt8(const float* f) {
  f32x4 u = *(const f32x4*)f, v = *(const f32x4*)(f + 4);
  bf16x8 r;
  r[0] = (__bf16)u[0]; r[1] = (__bf16)u[1]; r[2] = (__bf16)u[2]; r[3] = (__bf16)u[3];
  r[4] = (__bf16)v[0]; r[5] = (__bf16)v[1]; r[6] = (__bf16)v[2]; r[7] = (__bf16)v[3];
  return r;
}

// ---------------------------------------------------------------------------
// Dtype probe (fp32 vs bf16 inputs) -> flag in d_ws.
// ---------------------------------------------------------------------------
__global__ void detect(const ushort_t* w, unsigned* flag) {
  if (threadIdx.x == 0) {
    unsigned f = 0;
    for (int i = 0; i < 128; ++i) {
      float v = b2f(w[i]);
      if (!(v * v < 1.f)) f = 1;    // catches NaN too
    }
    *flag = f;
  }
}

// ---------------------------------------------------------------------------
// Recurrent kernel — tag-in-data (seqlock) synchronization.
//  bg = wg & 15 owns batch rows [bg*16,+16); ug = wg >> 4 owns units
//  [ug*32,+32) x 4 gates; wave w owns a 16x16 output tile.
// h published as u64 = {u32 pair of bf16, u32 step-tag}, relaxed agent-scope
// atomics (LLC). Consumer stage loads chunks and checks embedded tags —
// detect and data transfer are ONE LLC access. No flags, no vmcnt drain,
// no pre-publish barrier. 2 intra-WG barriers per step.
// WAR safety (double-buffered slots, no flags): X stores h(t+1) only after
// staging h(t), which required every Y's h(t) store, which Y issued after
// its own stage loads of h(t-1) (same slot) completed (they fed Y's MFMAs).
// Exact tag match (== bstep) + slot parity: stale tag (t-2) -> retry;
// future tag (t+2) provably impossible.
// ---------------------------------------------------------------------------
__global__ __launch_bounds__(NT, 2) void lstm_seq(
    const void* enc_inp, const void* dec_inp,
    const void* eWih, const void* eWhh, const void* ebih, const void* ebhh,
    const void* dWih, const void* dWhh, const void* dbih, const void* dbhh,
    u64* slot0, u64* slot1,
    void* dout, const unsigned* mode)
{
  __shared__ __align__(16) char Hs[16384];       // staged h, XOR-swizzled
  __shared__ __align__(16) float Zs[8][16][20];  // per-wave z slab (wave-local)
  __shared__ float Bias[128];

  const bool f32m = (*mode != 0);
  char* hid = (char*)dout + (size_t)B * TDEC * OD * (f32m ? 4 : 2);

  const int tid = threadIdx.x;
  const int lane = tid & 63;
  const int w = tid >> 6;
  const int wg = blockIdx.x;
  const int bg = wg & 15;          // batch group (members share XCD, perf only)
  const int ug = wg >> 4;          // unit group
  const int fm = lane & 15;
  const int q = lane >> 4;
  const int row0 = bg * 16;
  const int u0w = ug * 32 + w * 4;

  // cell-update lane mapping: one (row, unit) pair per lane, c in register
  const int crow = lane >> 2;
  const int cdu = lane & 3;
  float creg = 0.f;

  // producer u64 slot index: [ug][row0+crow][pair w*2 + (cdu>>1)]
  const size_t pidx = (size_t)ug * 4096 + (size_t)(row0 + crow) * 16
                    + (size_t)(w * 2) + (cdu >> 1);

  bf16x8 bfrag[KI];
  unsigned bstep = 0;

  for (int phase = 0; phase < 2; ++phase) {
    const void* Wih = phase ? dWih : eWih;
    const void* Whh = phase ? dWhh : eWhh;
    const void* bih = phase ? dbih : ebih;
    const void* bhh = phase ? dbhh : ebhh;
    const void* xin = phase ? dec_inp : enc_inp;
    const int T = phase ? TDEC : TENC;
    const int xstr = phase ? (TDEC * DIN) : (TENC * DIN);   // elements

    // per-wave weight fragments straight from global (once per phase)
    {
      const int grow = (fm >> 2) * HD + u0w + (fm & 3);
      for (int i = 0; i < KI; ++i) {
        union { ushort_t s[8]; bf16x8 v; } uf;
        const int k0 = i * 32 + q * 8;
#pragma unroll
        for (int e = 0; e < 8; ++e) {
          const int k = k0 + e;
          float wv = (k < HD) ? ld_elem(Whh, (size_t)grow * HD + k, f32m)
                              : ld_elem(Wih, (size_t)grow * DIN + (k - HD), f32m);
          uf.s[e] = f2b(wv);
        }
        bfrag[i] = uf.v;
      }
    }
    __syncthreads();   // all waves past last Bias read of previous phase
    if (tid < 128) {
      const int w_ = tid >> 4, n = tid & 15;
      const int grow = (n >> 2) * HD + ug * 32 + w_ * 4 + (n & 3);
      Bias[tid] = ld_elem(bih, grow, f32m) + ld_elem(bhh, grow, f32m);
    }
    __syncthreads();   // Bias ready

    for (int t = 0; t < T; ++t) {
      const u64* sslot = (bstep & 1) ? slot1 : slot0;
      u64* dslot = (bstep & 1) ? slot0 : slot1;

      // ---- x-part first (independent of h) ----
      f32x4 acca = {0.f, 0.f, 0.f, 0.f}, accb = {0.f, 0.f, 0.f, 0.f};
      if (!f32m) {
        const ushort_t* x0 = (const ushort_t*)xin + (size_t)(row0 + fm) * xstr + t * DIN;
        bf16x8 a0 = *(const bf16x8*)(x0 + q * 8);
        bf16x8 a1 = *(const bf16x8*)(x0 + 32 + q * 8);
        acca = __builtin_amdgcn_mfma_f32_16x16x32_bf16(a0, bfrag[16], acca, 0, 0, 0);
        accb = __builtin_amdgcn_mfma_f32_16x16x32_bf16(a1, bfrag[17], accb, 0, 0, 0);
      } else {
        const float* x0 = (const float*)xin + (size_t)(row0 + fm) * xstr + t * DIN;
        bf16x8 a0 = cvt8(x0 + q * 8);
        bf16x8 a1 = cvt8(x0 + 32 + q * 8);
        acca = __builtin_amdgcn_mfma_f32_16x16x32_bf16(a0, bfrag[16], acca, 0, 0, 0);
        accb = __builtin_amdgcn_mfma_f32_16x16x32_bf16(a1, bfrag[17], accb, 0, 0, 0);
      }

      __syncthreads();   // all waves done reading Hs of previous step

      // ---- stage + detect fused: tag-checked chunk loads -> LDS ----
      // chunk c covers (ug = c>>7, r = (c>>3)&15, pair-pair pr = c&7):
      // 2 u64 = 2 {pair,tag} = 4 units of row row0+r. c = tid + 512*j is
      // wave-coalesced (consecutive lanes -> consecutive 16B).
      {
        const unsigned tag = bstep;
        unsigned done = 0;
        do {
#pragma unroll
          for (int j = 0; j < 4; ++j) {
            if (done & (1u << j)) continue;
            const int c = tid + (j << 9);
            const int ugs = c >> 7, r = (c >> 3) & 15, pr = c & 7;
            const u64* p = sslot + ((size_t)ugs * 4096
                                    + (size_t)(row0 + r) * 16 + (pr << 1));
            u64 a = __hip_atomic_load(p,     __ATOMIC_RELAXED, __HIP_MEMORY_SCOPE_AGENT);
            u64 b = __hip_atomic_load(p + 1, __ATOMIC_RELAXED, __HIP_MEMORY_SCOPE_AGENT);
            if ((unsigned)(a >> 32) == tag && (unsigned)(b >> 32) == tag) {
              const int od = (ugs * 1024 + r * 64 + pr * 8) ^ ((r & 7) << 4);
              uint2 v; v.x = (unsigned)a; v.y = (unsigned)b;
              *(uint2*)(Hs + od) = v;
              done |= 1u << j;
            }
          }
          if (done != 15u) __builtin_amdgcn_s_sleep(1);
        } while (done != 15u);
      }
      __syncthreads();   // Hs ready

      // ---- 16 h-MFMAs, dual accumulator chains ----
      const int sw = (fm & 7) << 4;
#pragma unroll
      for (int i = 0; i < 16; i += 2) {
        bf16x8 a0 = *(const bf16x8*)(Hs + ((i * 1024 + fm * 64 + q * 16) ^ sw));
        bf16x8 a1 = *(const bf16x8*)(Hs + (((i + 1) * 1024 + fm * 64 + q * 16) ^ sw));
        acca = __builtin_amdgcn_mfma_f32_16x16x32_bf16(a0, bfrag[i],     acca, 0, 0, 0);
        accb = __builtin_amdgcn_mfma_f32_16x16x32_bf16(a1, bfrag[i + 1], accb, 0, 0, 0);
      }
      f32x4 acc = acca + accb;

      // z -> wave-private LDS slab; C/D layout: col=fm, row=q*4+r
#pragma unroll
      for (int r = 0; r < 4; ++r)
        Zs[w][q * 4 + r][fm] = acc[r];

      // cell update: lane -> (row = crow, unit = u0w + cdu); c in register
      float h2;
      {
        const float* zr = Zs[w][crow];
        float zi = zr[cdu]      + Bias[w * 16 + cdu];
        float zf = zr[4 + cdu]  + Bias[w * 16 + 4 + cdu];
        float zg = zr[8 + cdu]  + Bias[w * 16 + 8 + cdu];
        float zo = zr[12 + cdu] + Bias[w * 16 + 12 + cdu];
        float c2 = sigmf(zf) * creg + sigmf(zi) * tanhf_fast(zg);
        h2 = sigmf(zo) * tanhf_fast(c2);
        creg = c2;
      }
      // pack (cdu, cdu+1) pairs; publish {pair, tag=bstep+1} from even-cdu
      // lanes — tag travels with the data, no drain/flag needed.
      float hn = __shfl_xor(h2, 1);
      unsigned pk = (unsigned)f2b(h2) | ((unsigned)f2b(hn) << 16);
      if ((cdu & 1) == 0) {
        u64 val = (u64)pk | ((u64)(bstep + 1) << 32);
        __hip_atomic_store(dslot + pidx, val,
                           __ATOMIC_RELAXED, __HIP_MEMORY_SCOPE_AGENT);
      }

      // decoder hidden-state output (off the sync path entirely)
      if (phase && (cdu & 1) == 0) {
        size_t off = ((size_t)(row0 + crow) * TDEC + t) * HD + u0w + cdu;
        if (f32m) {
          float2 f2; f2.x = h2; f2.y = hn;
          *(float2*)((float*)hid + off) = f2;
        } else {
          *(unsigned*)((ushort_t*)hid + off) = pk;
        }
      }
      ++bstep;
    }
  }
}

// ---------------------------------------------------------------------------
// Output projection: Y[16384x512] = Hd[16384x512] @ out_W^T + out_b.
// ---------------------------------------------------------------------------
__global__ __launch_bounds__(NT, 2) void out_proj(
    const void* Wo, const void* bo, void* dout, const unsigned* mode)
{
  __shared__ __align__(16) ushort_t Wc[16][520];
  const bool f32m = (*mode != 0);
  char* Ybase = (char*)dout;
  const char* Hd = Ybase + (size_t)B * TDEC * OD * (f32m ? 4 : 2);

  const int tid = threadIdx.x, lane = tid & 63, w = tid >> 6;
  const int fm = lane & 15, q = lane >> 4;
  const int nb = blockIdx.x & 31, mb = blockIdx.x >> 5;
  const int m0 = mb * 256, n0 = nb * 16;

  for (int idx = tid; idx < 16 * 512; idx += NT) {
    int n = idx >> 9, k = idx & 511;
    Wc[n][k] = f2b(ld_elem(Wo, (size_t)(n0 + n) * 512 + k, f32m));
  }
  __syncthreads();
  bf16x8 bfrag[16];
#pragma unroll
  for (int i = 0; i < 16; ++i) bfrag[i] = *(const bf16x8*)&Wc[fm][i * 32 + q * 8];

  f32x4 acc0 = {0.f, 0.f, 0.f, 0.f}, acc1 = {0.f, 0.f, 0.f, 0.f};
  if (!f32m) {
    const ushort_t* a0p = (const ushort_t*)Hd + (size_t)(m0 + w * 32 + fm) * 512;
    const ushort_t* a1p = (const ushort_t*)Hd + (size_t)(m0 + w * 32 + 16 + fm) * 512;
#pragma unroll
    for (int i = 0; i < 16; ++i) {
      int ko = i * 32 + q * 8;
      bf16x8 a0 = *(const bf16x8*)(a0p + ko);
      bf16x8 a1 = *(const bf16x8*)(a1p + ko);
      acc0 = __builtin_amdgcn_mfma_f32_16x16x32_bf16(a0, bfrag[i], acc0, 0, 0, 0);
      acc1 = __builtin_amdgcn_mfma_f32_16x16x32_bf16(a1, bfrag[i], acc1, 0, 0, 0);
    }
  } else {
    const float* a0p = (const float*)Hd + (size_t)(m0 + w * 32 + fm) * 512;
    const float* a1p = (const float*)Hd + (size_t)(m0 + w * 32 + 16 + fm) * 512;
#pragma unroll
    for (int i = 0; i < 16; ++i) {
      int ko = i * 32 + q * 8;
      bf16x8 a0 = cvt8(a0p + ko);
      bf16x8 a1 = cvt8(a1p + ko);
      acc0 = __builtin_amdgcn_mfma_f32_16x16x32_bf16(a0, bfrag[i], acc0, 0, 0, 0);
      acc1 = __builtin_amdgcn_mfma_f32_16x16x32_bf16(a1, bfrag[i], acc1, 0, 0, 0);
    }
  }
  float bias = ld_elem(bo, n0 + fm, f32m);
#pragma unroll
  for (int r = 0; r < 4; ++r) {
    size_t off0 = (size_t)(m0 + w * 32 + q * 4 + r) * 512 + n0 + fm;
    size_t off1 = off0 + (size_t)16 * 512;
    float v0 = acc0[r] + bias, v1 = acc1[r] + bias;
    if (f32m) { ((float*)Ybase)[off0] = v0; ((float*)Ybase)[off1] = v1; }
    else      { ((ushort_t*)Ybase)[off0] = f2b(v0); ((ushort_t*)Ybase)[off1] = f2b(v1); }
  }
}

extern "C" void kernel_launch(void* const* d_in, const int* in_sizes, int n_in,
                              void* d_out, int out_size, void* d_ws, size_t ws_size,
                              hipStream_t stream) {
  (void)in_sizes; (void)n_in; (void)out_size; (void)ws_size;
  const void* enc_inp = d_in[0];
  const void* dec_inp = d_in[1];
  const void* eWih = d_in[2];
  const void* eWhh = d_in[3];
  const void* ebih = d_in[4];
  const void* ebhh = d_in[5];
  const void* dWih = d_in[6];
  const void* dWhh = d_in[7];
  const void* dbih = d_in[8];
  const void* dbhh = d_in[9];
  const void* outW = d_in[10];
  const void* outb = d_in[11];

  unsigned* flag = (unsigned*)d_ws;

  // scratch inside the dec_outputs region of d_out (overwritten by out_proj):
  //   [64K, 64K+512K)   : h slot0  [ug 16][row 256][pair 16] u64 {pair, tag}
  //   [576K, 576K+512K) : h slot1
  char* ob = (char*)d_out;
  u64* slot0 = (u64*)(ob + 65536);
  u64* slot1 = (u64*)(ob + 65536 + (size_t)SLOTQ * 8);

  // zero both slots: gives h(0)=0 with tag 0 (slot0) and un-matchable tags
  // in slot1 until genuinely written at step 0
  hipMemsetAsync(d_out, 0, 65536 + 2 * (size_t)SLOTQ * 8, stream);

  detect<<<1, 64, 0, stream>>>((const ushort_t*)eWhh, flag);
  lstm_seq<<<GG, NT, 0, stream>>>(enc_inp, dec_inp, eWih, eWhh, ebih, ebhh,
                                  dWih, dWhh, dbih, dbhh,
                                  slot0, slot1, d_out, flag);
  out_proj<<<dim3(64 * 32), NT, 0, stream>>>(outW, outb, d_out, flag);
}